// Round 7
// baseline (14.183 us; speedup 1.0000x reference)
//
#include <hip/hip_runtime.h>

// GlassBlur (ImageNet-C) sigma=0.05 -> gaussian radius 0 -> blur is identity.
// Op == 49284 sequential pixel swaps == one exact permutation of fp32 values.
//
// Single kernel, no grid sync, no workspace. For swap-row h the 222 swaps
// compose into a segment permutation over rows {h-1,h}; closed form of the
// 4-register window machine (only the bottom occupant B propagates, through
// runs of code 01 = (dy=0,dx=-1)):
//   entry(qc): i=223-qc, ci=code(i), cm=code(i-1), run=run01 below idx
//     top   : ci==2 -> (h, qc+run(i)); cm==3 -> (h, qc+1+run(i-1)); else (h-1,qc)
//     bottom: ci==0 -> (h, qc+run(i)); ci==1 -> (h,qc-1); ci==3 -> (h-1,qc-1)
//             ci==2 -> cm==3 ? (h, qc+1+run(i-1)) : (h-1, qc)
//   qc==0/1 collapse into the same formulas when mask bits >=222 are zero
//   (verified algebraically against the exact window machine).
// Only the FIRST segment step (h=r, r>=2) is a bottom entry; later steps are
// top entries (cheap path). 224 blocks x 256 threads, thread t owns column t;
// each of the 4 waves chases independently (own ballots, no __syncthreads).
// R7: depth-2 software prefetch of segment codes -> dxy load latency is
// covered by two iterations of VALU work instead of one.

static constexpr int IMH = 224;
static constexpr int IMW = 224;
static constexpr int NSW = 49284;    // total swap count

typedef unsigned long long u64;

__device__ __forceinline__ u64 sel4(u64 m0, u64 m1, u64 m2, u64 m3, int c) {
    u64 a = (c & 1) ? m1 : m0;
    u64 b = (c & 1) ? m3 : m2;
    return (c & 2) ? b : a;
}

__device__ __forceinline__ int getbit4(u64 m0, u64 m1, u64 m2, u64 m3, int j) {
    return (int)((sel4(m0, m1, m2, m3, j >> 6) >> (j & 63)) & 1ull);
}

// run of consecutive set bits at positions i-1, i-2, ...  (i in [0,223])
__device__ __forceinline__ int run_below(u64 p0, u64 p1, u64 p2, u64 p3, int i) {
    int c = i >> 6, b = i & 63;
    u64 lo = sel4(p0, p1, p2, p3, c);
    u64 lw = (c > 0) ? sel4(p0, p1, p2, p3, c - 1) : 0ull;
    u64 val = b ? ((lo << (64 - b)) | (lw >> b)) : lw;
    u64 nv = ~val;
    int k = nv ? __builtin_clzll(nv) : 64;
    if (k >= 64) {                       // run crosses the 64-bit window (rare)
        while (k < i && getbit4(p0, p1, p2, p3, i - 1 - k)) ++k;
    }
    return k;
}

__global__ __launch_bounds__(256) void glass_onepass(const float* __restrict__ img,
                                                     const int2* __restrict__ dxy,
                                                     float* __restrict__ out) {
    int r = blockIdx.x;                  // output image row
    int t = threadIdx.x;                 // 0..255; owns column t (if < 224)
    int lane = t & 63;
    int c = t;

    int s = (r << 8) | c;                // chase state: (row<<8)|col
    bool a = (r >= 1) && (c < IMW);

    int h = (r < 2) ? 2 : r;             // first segment whose domain {h-1,h} holds r
    bool bottom = (r >= 2);              // first step sees the pixel in row h (bottom)

    // depth-2 pipeline: cur = seg h codes, nxt = seg h+1 codes
    int2 c0 = {0,0}, c1 = {0,0}, c2 = {0,0}, c3 = {0,0};
    int2 e0 = {0,0}, e1 = {0,0}, e2 = {0,0}, e3 = {0,0};
    if (r >= 1) {
        int b0 = (223 - h) * 222;
        c0 = dxy[b0 + lane];
        c1 = dxy[b0 + lane + 64];
        c2 = dxy[b0 + lane + 128];
        c3 = dxy[min(b0 + lane + 192, NSW - 1)];
        int b1 = (223 - min(h + 1, 223)) * 222;
        e0 = dxy[b1 + lane];
        e1 = dxy[b1 + lane + 64];
        e2 = dxy[b1 + lane + 128];
        e3 = dxy[min(b1 + lane + 192, NSW - 1)];
    }

    while (h <= 223 && __any((int)a)) {
        // issue prefetch of segment h+2 first (consumed two iterations later)
        int nb = (223 - min(h + 2, 223)) * 222;
        int2 n0 = dxy[nb + lane];
        int2 n1 = dxy[nb + lane + 64];
        int2 n2 = dxy[nb + lane + 128];
        int2 n3 = dxy[min(nb + lane + 192, NSW - 1)];

        // per-wave code masks for segment h (positions >= 222 forced to zero)
        u64 y0 = __ballot(c0.y < 0), x0 = __ballot(c0.x < 0);
        u64 y1 = __ballot(c1.y < 0), x1 = __ballot(c1.x < 0);
        u64 y2 = __ballot(c2.y < 0), x2 = __ballot(c2.x < 0);
        u64 y3 = __ballot(c3.y < 0) & 0x3fffffffull;
        u64 x3 = __ballot(c3.x < 0) & 0x3fffffffull;
        u64 p0 = ~y0 & x0, p1 = ~y1 & x1, p2 = ~y2 & x2, p3 = ~y3 & x3;

        if (a) {
            int qc = s & 255;
            int i = 223 - qc;
            int yi = getbit4(y0, y1, y2, y3, i);
            int xi = getbit4(x0, x1, x2, x3, i);
            int cm3 = (i > 0) ? (getbit4(y0, y1, y2, y3, i - 1) &
                                 getbit4(x0, x1, x2, x3, i - 1)) : 0;
            int row, col;
            if (bottom) {                // wave-uniform: first iteration only
                int ci = 2 * yi + xi;
                int idx = (ci == 0) ? i : max(i - 1, 0);
                int run = run_below(p0, p1, p2, p3, idx);
                if (ci == 0)      { row = h;     col = qc + run; }
                else if (ci == 1) { row = h;     col = qc - 1; }
                else if (ci == 3) { row = h - 1; col = qc - 1; }
                else {               // ci == 2 -> incoming top occupant
                    if (cm3) { row = h;     col = qc + 1 + run; }
                    else     { row = h - 1; col = qc; }
                }
            } else {                     // top entry: cheap path
                int ci2 = yi & (xi ^ 1);
                int idx = ci2 ? i : max(i - 1, 0);
                int run = run_below(p0, p1, p2, p3, idx);
                if (ci2)      { row = h;     col = qc + run; }
                else if (cm3) { row = h;     col = qc + 1 + run; }
                else          { row = h - 1; col = qc; }
            }
            s = (row << 8) | col;
            a = (row == h);              // stays in domain of segment h+1 (as top)
        }
        bottom = false;
        c0 = e0; c1 = e1; c2 = e2; c3 = e3;
        e0 = n0; e1 = n1; e2 = n2; e3 = n3;
        ++h;
    }

    if (c < IMW) {                       // exact fp32 gather + clamp
        int q = (s >> 8) * IMW + (s & 255);
        int p = r * IMW + c;
        float v0 = img[3 * q + 0];
        float v1 = img[3 * q + 1];
        float v2 = img[3 * q + 2];
        out[3 * p + 0] = fminf(fmaxf(v0, 0.0f), 1.0f);
        out[3 * p + 1] = fminf(fmaxf(v1, 0.0f), 1.0f);
        out[3 * p + 2] = fminf(fmaxf(v2, 0.0f), 1.0f);
    }
}

extern "C" void kernel_launch(void* const* d_in, const int* in_sizes, int n_in,
                              void* d_out, int out_size, void* d_ws, size_t ws_size,
                              hipStream_t stream) {
    const float* img = (const float*)d_in[0];
    const int2* dxy = (const int2*)d_in[1];
    float* out = (float*)d_out;
    hipLaunchKernelGGL(glass_onepass, dim3(IMH), dim3(256), 0, stream, img, dxy, out);
}

// Round 8
// 13.703 us; speedup vs baseline: 1.0350x; 1.0350x over previous
//
#include <hip/hip_runtime.h>

// GlassBlur (ImageNet-C) sigma=0.05 -> gaussian radius 0 -> blur is identity.
// Op == 49284 sequential pixel swaps == one exact permutation of fp32 values.
//
// Single kernel, no grid sync, no workspace. For swap-row h the 222 swaps
// compose into a segment permutation over rows {h-1,h}; closed form of the
// 4-register window machine (only the bottom occupant B propagates, through
// runs of code 01 = (dy=0,dx=-1)):
//   entry(qc): i=223-qc, ci=code(i), cm=code(i-1), run=run01 below idx
//     top   : ci==2 -> (h, qc+run(i)); cm==3 -> (h, qc+1+run(i-1)); else (h-1,qc)
//     bottom: ci==0 -> (h, qc+run(i)); ci==1 -> (h,qc-1); ci==3 -> (h-1,qc-1)
//             ci==2 -> cm==3 ? (h, qc+1+run(i-1)) : (h-1, qc)
//   qc==0/1 collapse into the same formulas when mask bits >=222 are zero
//   (verified algebraically against the exact window machine).
// Only the FIRST segment step (h=r, r>=2) is a bottom entry; all later steps
// are top entries (pixel row == h means top of segment h+1) -> cheap path.
// 224 blocks x 256 threads: thread t owns column t; each of the 4 waves
// chases independently (own ballot masks, own loop, no __syncthreads).
// R8 = R6 verbatim (best measured: 13.59 us). R7's depth-2 prefetch regressed
// (−4%): loop is not latency-exposed; single-dispatch replay floor dominates.

static constexpr int IMH = 224;
static constexpr int IMW = 224;
static constexpr int NSW = 49284;    // total swap count

typedef unsigned long long u64;

__device__ __forceinline__ u64 sel4(u64 m0, u64 m1, u64 m2, u64 m3, int c) {
    u64 a = (c & 1) ? m1 : m0;
    u64 b = (c & 1) ? m3 : m2;
    return (c & 2) ? b : a;
}

__device__ __forceinline__ int getbit4(u64 m0, u64 m1, u64 m2, u64 m3, int j) {
    return (int)((sel4(m0, m1, m2, m3, j >> 6) >> (j & 63)) & 1ull);
}

// run of consecutive set bits at positions i-1, i-2, ...  (i in [0,223])
__device__ __forceinline__ int run_below(u64 p0, u64 p1, u64 p2, u64 p3, int i) {
    int c = i >> 6, b = i & 63;
    u64 lo = sel4(p0, p1, p2, p3, c);
    u64 lw = (c > 0) ? sel4(p0, p1, p2, p3, c - 1) : 0ull;
    u64 val = b ? ((lo << (64 - b)) | (lw >> b)) : lw;
    u64 nv = ~val;
    int k = nv ? __builtin_clzll(nv) : 64;
    if (k >= 64) {                       // run crosses the 64-bit window (rare)
        while (k < i && getbit4(p0, p1, p2, p3, i - 1 - k)) ++k;
    }
    return k;
}

__global__ __launch_bounds__(256) void glass_onepass(const float* __restrict__ img,
                                                     const int2* __restrict__ dxy,
                                                     float* __restrict__ out) {
    int r = blockIdx.x;                  // output image row
    int t = threadIdx.x;                 // 0..255; owns column t (if < 224)
    int lane = t & 63;
    int c = t;

    int s = (r << 8) | c;                // chase state: (row<<8)|col
    bool a = (r >= 1) && (c < IMW);

    int h = (r < 2) ? 2 : r;             // first segment whose domain {h-1,h} holds r
    bool bottom = (r >= 2);              // first step sees the pixel in row h (bottom)
    int base = (223 - h) * 222;
    int2 d0 = {0,0}, d1 = {0,0}, d2 = {0,0}, d3 = {0,0};
    if (r >= 1) {
        d0 = dxy[base + lane];
        d1 = dxy[base + lane + 64];
        d2 = dxy[base + lane + 128];
        d3 = dxy[min(base + lane + 192, NSW - 1)];
    }

    while (h <= 223 && __any((int)a)) {
        // per-wave code masks for segment h (positions >= 222 forced to zero)
        u64 y0 = __ballot(d0.y < 0), x0 = __ballot(d0.x < 0);
        u64 y1 = __ballot(d1.y < 0), x1 = __ballot(d1.x < 0);
        u64 y2 = __ballot(d2.y < 0), x2 = __ballot(d2.x < 0);
        u64 y3 = __ballot(d3.y < 0) & 0x3fffffffull;
        u64 x3 = __ballot(d3.x < 0) & 0x3fffffffull;
        u64 p0 = ~y0 & x0, p1 = ~y1 & x1, p2 = ~y2 & x2, p3 = ~y3 & x3;

        // prefetch next segment's codes (clamped; unused if h==223)
        int nb = (223 - min(h + 1, 223)) * 222;
        int2 n0 = dxy[nb + lane];
        int2 n1 = dxy[nb + lane + 64];
        int2 n2 = dxy[nb + lane + 128];
        int2 n3 = dxy[min(nb + lane + 192, NSW - 1)];

        if (a) {
            int qc = s & 255;
            int i = 223 - qc;
            int yi = getbit4(y0, y1, y2, y3, i);
            int xi = getbit4(x0, x1, x2, x3, i);
            int cm3 = (i > 0) ? (getbit4(y0, y1, y2, y3, i - 1) &
                                 getbit4(x0, x1, x2, x3, i - 1)) : 0;
            int row, col;
            if (bottom) {                // wave-uniform: first iteration only
                int ci = 2 * yi + xi;
                int idx = (ci == 0) ? i : max(i - 1, 0);
                int run = run_below(p0, p1, p2, p3, idx);
                if (ci == 0)      { row = h;     col = qc + run; }
                else if (ci == 1) { row = h;     col = qc - 1; }
                else if (ci == 3) { row = h - 1; col = qc - 1; }
                else {               // ci == 2 -> incoming top occupant
                    if (cm3) { row = h;     col = qc + 1 + run; }
                    else     { row = h - 1; col = qc; }
                }
            } else {                     // top entry: cheap path
                int ci2 = yi & (xi ^ 1);
                int idx = ci2 ? i : max(i - 1, 0);
                int run = run_below(p0, p1, p2, p3, idx);
                if (ci2)      { row = h;     col = qc + run; }
                else if (cm3) { row = h;     col = qc + 1 + run; }
                else          { row = h - 1; col = qc; }
            }
            s = (row << 8) | col;
            a = (row == h);              // stays in domain of segment h+1 (as top)
        }
        bottom = false;
        d0 = n0; d1 = n1; d2 = n2; d3 = n3;
        ++h;
    }

    if (c < IMW) {                       // exact fp32 gather + clamp
        int q = (s >> 8) * IMW + (s & 255);
        int p = r * IMW + c;
        float v0 = img[3 * q + 0];
        float v1 = img[3 * q + 1];
        float v2 = img[3 * q + 2];
        out[3 * p + 0] = fminf(fmaxf(v0, 0.0f), 1.0f);
        out[3 * p + 1] = fminf(fmaxf(v1, 0.0f), 1.0f);
        out[3 * p + 2] = fminf(fmaxf(v2, 0.0f), 1.0f);
    }
}

extern "C" void kernel_launch(void* const* d_in, const int* in_sizes, int n_in,
                              void* d_out, int out_size, void* d_ws, size_t ws_size,
                              hipStream_t stream) {
    const float* img = (const float*)d_in[0];
    const int2* dxy = (const int2*)d_in[1];
    float* out = (float*)d_out;
    hipLaunchKernelGGL(glass_onepass, dim3(IMH), dim3(256), 0, stream, img, dxy, out);
}